// Round 5
// baseline (685.760 us; speedup 1.0000x reference)
//
#include <hip/hip_runtime.h>

#define T 252
#define NOUT 500
#define NSEL 20
#define UBV 0.1f

// LDS activation planes: [row = 16 zero-pad + 256 t][64 ch bf16 = 128 B], XOR-swizzled
// 16B chunks: chunk' = chunk ^ (row & 7). Row stride 32 dwords, 272 rows, 2 planes.
#define ROWS 272
#define PLANE_U (ROWS * 32)           // 8704 uints per plane
#define LDS_BYTES (2 * PLANE_U * 4)   // 69632 B

// ws layout (floats):
//   [0)        AF : W MFMA A-frags, 384 frags x 256 dwords    98304
//   [98304)    awT : attn_w^T [c][a]                          32000
//   [130304)   fwT : fc_w^T   [c][a]                          32000
//   [162304)   pooled [B][64]                                 131072
#define OFF_AWT    98304
#define OFF_FWT    130304
#define OFF_POOLED 162304

typedef short bf8 __attribute__((ext_vector_type(8)));   // 8 bf16 = 4 VGPR
typedef float f32x4 __attribute__((ext_vector_type(4)));

static __device__ __forceinline__ unsigned short f2bf(float f) {
    unsigned u = __float_as_uint(f);
    return (unsigned short)((u + 0x7fffu + ((u >> 16) & 1u)) >> 16);   // RNE
}
static __device__ __forceinline__ float bf2f(unsigned short h) {
    return __uint_as_float(((unsigned)h) << 16);
}
// uint index of 16B chunk base, swizzled
static __device__ __forceinline__ int swz(int row, int chunk) {
    return row * 32 + ((chunk ^ (row & 7)) << 2);
}

// ---------- prep: pack W into A-fragments + head transposes ----------
// fragid = ((((buf*4+lvl)*2+Kt)*3+tap)*4+m)*2+s ; per frag: [lane][4 dwords]
// A-frag lane map (16x16x32 bf16): c = m*16 + (lane&15), i = Kt*32 + (lane>>4)*8 + j
__global__ __launch_bounds__(256) void prep_kernel(
    const float* __restrict__ w1, const float* __restrict__ w2,
    const float* __restrict__ aw, const float* __restrict__ fw,
    float* __restrict__ ws)
{
    int gid = blockIdx.x * 256 + threadIdx.x;
    if (gid < 24576) {
        int frag = gid >> 6, lane = gid & 63;
        int s   = frag & 1;
        int m   = (frag >> 1) & 3;
        int t3  = frag >> 3;
        int tap = t3 % 3;
        int q   = t3 / 3;
        int Kt  = q & 1;
        int lvl = (q >> 1) & 3;
        int buf = q >> 3;
        int c  = m * 16 + (lane & 15);
        int i0 = Kt * 32 + (lane >> 4) * 8;
        const float* W = (buf ? w2 : w1) + lvl * 12288 + c * 192;
        unsigned short v[8];
        for (int j = 0; j < 8; ++j) {
            float x = W[(i0 + j) * 3 + tap];
            unsigned short hi = f2bf(x);
            if (s == 0) v[j] = hi;
            else        v[j] = f2bf(x - bf2f(hi));
        }
        unsigned* dst = (unsigned*)ws + frag * 256 + lane * 4;
        for (int d = 0; d < 4; ++d)
            dst[d] = (unsigned)v[2 * d] | ((unsigned)v[2 * d + 1] << 16);
    }
    if (gid < 32000) {
        int a = gid >> 6, c = gid & 63;   // src [a][c]
        ws[OFF_AWT + c * 500 + a] = aw[gid];
        ws[OFF_FWT + c * 500 + a] = fw[gid];
    }
}

extern __shared__ unsigned short lds[];

#define MFMA(A, B, C) __builtin_amdgcn_mfma_f32_16x16x32_bf16((A), (B), (C), 0, 0, 0)

__global__ __launch_bounds__(512, 2) void conv_kernel(
    const float* __restrict__ x,
    const float* __restrict__ ws,
    const float* __restrict__ b1,
    const float* __restrict__ b2,
    float* __restrict__ pooled)
{
    const int b    = blockIdx.x;
    const int tid  = threadIdx.x;        // 0..511
    const int lane = tid & 63;
    const int wv   = tid >> 6;           // 8 waves; wave handles ntiles 2wv, 2wv+1

    unsigned* Lh = (unsigned*)lds;
    unsigned* Ll = Lh + PLANE_U;

    // zero pad rows 0..15 (t<0) and 268..271 (t>=252), both planes (whole rows)
    for (int j = tid; j < 640; j += 512) {
        int r20 = j >> 5, col = j & 31;
        int r = (r20 < 16) ? r20 : (252 + r20);
        Lh[r * 32 + col] = 0u;
        Ll[r * 32 + col] = 0u;
    }
    // ingest x[b]: [252][64] fp32 -> split hi/lo bf16 planes (swizzled)
    const float4* xb = (const float4*)(x + (size_t)b * (T * 64));
    for (int v = tid; v < T * 16; v += 512) {
        float4 xv = xb[v];
        int t = v >> 4, f4 = v & 15;              // channel base = 4*f4
        float vv[4] = {xv.x, xv.y, xv.z, xv.w};
        unsigned short h_[4], l_[4];
        #pragma unroll
        for (int r = 0; r < 4; ++r) {
            h_[r] = f2bf(vv[r]);
            l_[r] = f2bf(vv[r] - bf2f(h_[r]));
        }
        int row = 16 + t;
        int ui = swz(row, f4 >> 1) + ((f4 & 1) << 1);
        Lh[ui]     = (unsigned)h_[0] | ((unsigned)h_[1] << 16);
        Lh[ui + 1] = (unsigned)h_[2] | ((unsigned)h_[3] << 16);
        Ll[ui]     = (unsigned)l_[0] | ((unsigned)l_[1] << 16);
        Ll[ui + 1] = (unsigned)l_[2] | ((unsigned)l_[3] << 16);
    }
    __syncthreads();

    const uint4* AF4 = (const uint4*)ws;
    const int g    = lane >> 4;               // 0..3
    const int g4   = g << 2;
    const int ln16 = lane & 15;

    uint2 hh[4][2], hl[4][2];                 // saved h_old at D-tiles (hi/lo packed)

    for (int lvl = 0; lvl < 4; ++lvl) {
        const int d = 1 << lvl;
        for (int cv = 0; cv < 2; ++cv) {
            f32x4 acc[4][2];
            #pragma unroll
            for (int m = 0; m < 4; ++m)
                #pragma unroll
                for (int nn = 0; nn < 2; ++nn)
                    acc[m][nn] = (f32x4){0.f, 0.f, 0.f, 0.f};

            #pragma unroll
            for (int Kt = 0; Kt < 2; ++Kt) {
                #pragma unroll
                for (int tap = 0; tap < 3; ++tap) {
                    const int shift = (2 - tap) * d;
                    const int fb = (((cv * 4 + lvl) * 2 + Kt) * 3 + tap) * 8;
                    bf8 Bh[2], Bl[2];
                    #pragma unroll
                    for (int nn = 0; nn < 2; ++nn) {
                        int row = 16 + (2 * wv + nn) * 16 + ln16 - shift;
                        int ui  = swz(row, Kt * 4 + g);
                        Bh[nn] = *(const bf8*)(Lh + ui);
                        Bl[nn] = *(const bf8*)(Ll + ui);
                    }
                    #pragma unroll
                    for (int m = 0; m < 4; ++m) {
                        uint4 ta = AF4[(fb + 2 * m) * 64 + lane];
                        uint4 tb = AF4[(fb + 2 * m + 1) * 64 + lane];
                        bf8 Ah = *(bf8*)&ta;
                        bf8 Al = *(bf8*)&tb;
                        #pragma unroll
                        for (int nn = 0; nn < 2; ++nn) {
                            f32x4 a = acc[m][nn];
                            a = MFMA(Ah, Bh[nn], a);
                            a = MFMA(Ah, Bl[nn], a);   // hi*lo
                            a = MFMA(Al, Bh[nn], a);   // lo*hi  (lo*lo dropped: ~2^-18)
                            acc[m][nn] = a;
                        }
                    }
                }
            }

            // epilogue: D map: t = ntile*16 + ln16, c = m*16 + g4 + reg
            if (cv == 0) {
                #pragma unroll
                for (int m = 0; m < 4; ++m)
                    #pragma unroll
                    for (int nn = 0; nn < 2; ++nn) {
                        int row = 16 + (2 * wv + nn) * 16 + ln16;
                        int cd  = m * 8 + (g4 >> 1);
                        int ui  = swz(row, cd >> 2) + (cd & 3);
                        hh[m][nn] = *(uint2*)(Lh + ui);
                        hl[m][nn] = *(uint2*)(Ll + ui);
                    }
                __syncthreads();   // all reads of h_old done
                #pragma unroll
                for (int m = 0; m < 4; ++m) {
                    int c0 = m * 16 + g4;
                    float4 bv = *(const float4*)(b1 + lvl * 64 + c0);
                    float bb[4] = {bv.x, bv.y, bv.z, bv.w};
                    #pragma unroll
                    for (int nn = 0; nn < 2; ++nn) {
                        int row = 16 + (2 * wv + nn) * 16 + ln16;
                        int cd  = m * 8 + (g4 >> 1);
                        int ui  = swz(row, cd >> 2) + (cd & 3);
                        unsigned short h_[4], l_[4];
                        #pragma unroll
                        for (int r = 0; r < 4; ++r) {
                            float o = fmaxf(acc[m][nn][r] + bb[r], 0.f);
                            h_[r] = f2bf(o);
                            l_[r] = f2bf(o - bf2f(h_[r]));
                        }
                        uint2 wh, wl;
                        wh.x = (unsigned)h_[0] | ((unsigned)h_[1] << 16);
                        wh.y = (unsigned)h_[2] | ((unsigned)h_[3] << 16);
                        wl.x = (unsigned)l_[0] | ((unsigned)l_[1] << 16);
                        wl.y = (unsigned)l_[2] | ((unsigned)l_[3] << 16);
                        *(uint2*)(Lh + ui) = wh;
                        *(uint2*)(Ll + ui) = wl;
                    }
                }
                __syncthreads();   // o1 visible
            } else {
                __syncthreads();   // all reads of o1 done
                #pragma unroll
                for (int m = 0; m < 4; ++m) {
                    int c0 = m * 16 + g4;
                    float4 bv = *(const float4*)(b2 + lvl * 64 + c0);
                    float bb[4] = {bv.x, bv.y, bv.z, bv.w};
                    #pragma unroll
                    for (int nn = 0; nn < 2; ++nn) {
                        int row = 16 + (2 * wv + nn) * 16 + ln16;
                        int cd  = m * 8 + (g4 >> 1);
                        int ui  = swz(row, cd >> 2) + (cd & 3);
                        unsigned hx = hh[m][nn].x, hy = hh[m][nn].y;
                        unsigned lx = hl[m][nn].x, ly = hl[m][nn].y;
                        float hold[4] = {
                            bf2f((unsigned short)(hx & 0xffff)) + bf2f((unsigned short)(lx & 0xffff)),
                            bf2f((unsigned short)(hx >> 16))    + bf2f((unsigned short)(lx >> 16)),
                            bf2f((unsigned short)(hy & 0xffff)) + bf2f((unsigned short)(ly & 0xffff)),
                            bf2f((unsigned short)(hy >> 16))    + bf2f((unsigned short)(ly >> 16))};
                        unsigned short h_[4], l_[4];
                        #pragma unroll
                        for (int r = 0; r < 4; ++r) {
                            float o = fmaxf(acc[m][nn][r] + bb[r], 0.f);
                            float hn = fmaxf(o + hold[r], 0.f);
                            h_[r] = f2bf(hn);
                            l_[r] = f2bf(hn - bf2f(h_[r]));
                        }
                        uint2 wh, wl;
                        wh.x = (unsigned)h_[0] | ((unsigned)h_[1] << 16);
                        wh.y = (unsigned)h_[2] | ((unsigned)h_[3] << 16);
                        wl.x = (unsigned)l_[0] | ((unsigned)l_[1] << 16);
                        wl.y = (unsigned)l_[2] | ((unsigned)l_[3] << 16);
                        *(uint2*)(Lh + ui) = wh;
                        *(uint2*)(Ll + ui) = wl;
                    }
                }
                __syncthreads();   // h_new visible
            }
        }
    }

    // ---- max-pool over t (values >= 0 after relu) ----
    {
        int c = tid & 63, p = tid >> 6;        // 8 parts x 32 t
        int cd = c >> 1;
        float mx = 0.f;
        int n = (p == 7) ? 28 : 32;
        for (int j = 0; j < n; ++j) {
            int row = 16 + p * 32 + j;
            int ui = swz(row, cd >> 2) + (cd & 3);
            int us = 2 * ui + (c & 1);
            mx = fmaxf(mx, bf2f(lds[us]) + bf2f(lds[2 * PLANE_U + us]));
        }
        __syncthreads();
        ((float*)lds)[tid] = mx;
        __syncthreads();
        if (tid < 64) {
            float* fs = (float*)lds;
            float mm = fs[tid];
            #pragma unroll
            for (int q = 1; q < 8; ++q) mm = fmaxf(mm, fs[q * 64 + tid]);
            pooled[(size_t)b * 64 + tid] = mm;
        }
    }
}

__global__ __launch_bounds__(256) void head_kernel(
    const float* __restrict__ ws,
    const float* __restrict__ proj_w,
    const float* __restrict__ proj_b,
    const float* __restrict__ attn_b,
    const float* __restrict__ fc_b,
    float* __restrict__ out)
{
    const float* awT    = ws + OFF_AWT;
    const float* fwT    = ws + OFF_FWT;
    const float* pooled = ws + OFF_POOLED;

    __shared__ float z[64];
    __shared__ float rs[8];
    __shared__ unsigned long long ks[4];

    const int b   = blockIdx.x;
    const int tid = threadIdx.x;
    const int wv  = tid >> 6, ln = tid & 63;

    if (tid < 64) {
        float s = proj_b[tid];
        const float* pw = proj_w + tid * 64;
        const float* pl = pooled + (size_t)b * 64;
        #pragma unroll 8
        for (int c = 0; c < 64; ++c) s = fmaf(pw[c], pl[c], s);
        z[tid] = fmaxf(s, 0.f);
    }
    __syncthreads();

    const int a0  = tid;
    const int a1  = tid + 256;
    const int a1e = (a1 < NOUT) ? a1 : (NOUT - 1);

    float l0 = attn_b[a0], l1 = attn_b[a1e];
    #pragma unroll 8
    for (int c = 0; c < 64; ++c) {
        float zc = z[c];
        l0 = fmaf(zc, awT[c * 500 + a0],  l0);
        l1 = fmaf(zc, awT[c * 500 + a1e], l1);
    }
    float v0 = 1.f / (1.f + expf(-l0));
    float v1 = (a1 < NOUT) ? 1.f / (1.f + expf(-l1)) : 0.f;

    bool m0 = false, m1 = false;
    for (int s = 0; s < NSEL; ++s) {
        unsigned long long k0 = ((unsigned long long)__float_as_uint(v0) << 32)
                              | (unsigned)(0xFFFFFFFFu - (unsigned)a0);
        unsigned long long k1 = ((unsigned long long)__float_as_uint(v1) << 32)
                              | (unsigned)(0xFFFFFFFFu - (unsigned)a1);
        unsigned long long k = (k0 > k1) ? k0 : k1;
        for (int o = 32; o > 0; o >>= 1) {
            unsigned long long other = __shfl_xor(k, o);
            if (other > k) k = other;
        }
        if (ln == 0) ks[wv] = k;
        __syncthreads();
        unsigned long long kk = ks[0];
        if (ks[1] > kk) kk = ks[1];
        if (ks[2] > kk) kk = ks[2];
        if (ks[3] > kk) kk = ks[3];
        int wa = (int)(0xFFFFFFFFu - (unsigned)(kk & 0xFFFFFFFFu));
        if (wa == a0) { m0 = true; v0 = 0.f; }
        if (wa == a1) { m1 = true; v1 = 0.f; }
        __syncthreads();
    }

    float f0 = fc_b[a0], f1 = fc_b[a1e];
    #pragma unroll 8
    for (int c = 0; c < 64; ++c) {
        float zc = z[c];
        f0 = fmaf(zc, fwT[c * 500 + a0],  f0);
        f1 = fmaf(zc, fwT[c * 500 + a1e], f1);
    }
    if (a1 >= NOUT) f1 = -1e30f;

    float mx = fmaxf(f0, f1);
    for (int o = 32; o > 0; o >>= 1) mx = fmaxf(mx, __shfl_xor(mx, o));
    if (ln == 0) rs[wv] = mx;
    __syncthreads();
    mx = fmaxf(fmaxf(rs[0], rs[1]), fmaxf(rs[2], rs[3]));
    __syncthreads();

    float e0 = expf(f0 - mx);
    float e1 = (a1 < NOUT) ? expf(f1 - mx) : 0.f;
    float sm = e0 + e1;
    for (int o = 32; o > 0; o >>= 1) sm += __shfl_xor(sm, o);
    if (ln == 0) rs[wv] = sm;
    __syncthreads();
    float Z = rs[0] + rs[1] + rs[2] + rs[3];
    __syncthreads();

    float p0 = m0 ? (e0 / Z) : 0.f;
    float p1 = m1 ? (e1 / Z) : 0.f;
    float S = p0 + p1;
    for (int o = 32; o > 0; o >>= 1) S += __shfl_xor(S, o);
    if (ln == 0) rs[wv] = S;
    __syncthreads();
    S = rs[0] + rs[1] + rs[2] + rs[3];
    __syncthreads();

    float w0 = p0 / (S + 1e-8f);
    float w1 = p1 / (S + 1e-8f);

    for (int it = 0; it < 17; ++it) {
        float c0 = fminf(fmaxf(w0, 0.f), UBV);
        float c1 = fminf(fmaxf(w1, 0.f), UBV);
        float lo = (w0 - c0) + (w1 - c1);
        float ns = ((c0 != UBV) ? c0 : 0.f) + ((c1 != UBV) ? c1 : 0.f);
        for (int o = 32; o > 0; o >>= 1) {
            lo += __shfl_xor(lo, o);
            ns += __shfl_xor(ns, o);
        }
        if (ln == 0) { rs[wv * 2] = lo; rs[wv * 2 + 1] = ns; }
        __syncthreads();
        lo = rs[0] + rs[2] + rs[4] + rs[6];
        ns = rs[1] + rs[3] + rs[5] + rs[7];
        __syncthreads();
        if (ns == 0.f) ns = 1.f;
        w0 = (c0 != UBV) ? c0 + lo * c0 / ns : c0;
        w1 = (c1 != UBV) ? c1 + lo * c1 / ns : c1;
    }

    out[(size_t)b * 500 + a0] = w0;
    if (a1 < NOUT) out[(size_t)b * 500 + a1] = w1;
}

extern "C" void kernel_launch(void* const* d_in, const int* in_sizes, int n_in,
                              void* d_out, int out_size, void* d_ws, size_t ws_size,
                              hipStream_t stream)
{
    const float* x   = (const float*)d_in[0];
    const float* c1w = (const float*)d_in[1];
    const float* c1b = (const float*)d_in[2];
    const float* c2w = (const float*)d_in[3];
    const float* c2b = (const float*)d_in[4];
    const float* pw  = (const float*)d_in[5];
    const float* pb  = (const float*)d_in[6];
    const float* aw  = (const float*)d_in[7];
    const float* ab  = (const float*)d_in[8];
    const float* fw  = (const float*)d_in[9];
    const float* fb  = (const float*)d_in[10];

    float* ws  = (float*)d_ws;
    float* out = (float*)d_out;

    (void)hipFuncSetAttribute((const void*)conv_kernel,
                              hipFuncAttributeMaxDynamicSharedMemorySize,
                              LDS_BYTES);

    prep_kernel<<<128, 256, 0, stream>>>(c1w, c2w, aw, fw, ws);
    conv_kernel<<<2048, 512, LDS_BYTES, stream>>>(x, ws, c1b, c2b, ws + OFF_POOLED);
    head_kernel<<<2048, 256, 0, stream>>>(ws, pw, pb, ab, fb, out);
}

// Round 6
// 535.909 us; speedup vs baseline: 1.2796x; 1.2796x over previous
//
#include <hip/hip_runtime.h>
#include <hip/hip_bf16.h>

#define T 252
#define NOUT 500
#define NSEL 20
#define UBV 0.1f

// LDS activation planes: [row = 16 zero-pad + 256 t][64 ch bf16 = 128 B], XOR-swizzled
// 16B chunks: chunk' = chunk ^ (row & 7). Row stride 32 dwords, 272 rows, 2 planes.
#define ROWS 272
#define PLANE_U (ROWS * 32)           // 8704 uints per plane
#define LDS_BYTES (2 * PLANE_U * 4)   // 69632 B

// ws layout (floats):
//   [0)        AF : W MFMA A-frags, 384 frags x 256 dwords    98304
//   [98304)    awT : attn_w^T [c][a]                          32000
//   [130304)   fwT : fc_w^T   [c][a]                          32000
//   [162304)   pooled [B][64]                                 131072
#define OFF_AWT    98304
#define OFF_FWT    130304
#define OFF_POOLED 162304

typedef short bf8 __attribute__((ext_vector_type(8)));   // 8 bf16 = 4 VGPR
typedef float f32x4 __attribute__((ext_vector_type(4)));

static __device__ __forceinline__ unsigned short f2bf(float f) {
    unsigned u = __float_as_uint(f);
    return (unsigned short)((u + 0x7fffu + ((u >> 16) & 1u)) >> 16);   // RNE
}
static __device__ __forceinline__ float bf2f(unsigned short h) {
    return __uint_as_float(((unsigned)h) << 16);
}
// pack two floats -> two bf16 (RNE); lowers to v_cvt_pk_bf16_f32 where available
static __device__ __forceinline__ unsigned pk2bf(float a, float b) {
    __hip_bfloat162 h = __float22bfloat162_rn(float2{a, b});
    unsigned u; __builtin_memcpy(&u, &h, 4); return u;
}
static __device__ __forceinline__ float bf_lo_f(unsigned u) { return __uint_as_float(u << 16); }
static __device__ __forceinline__ float bf_hi_f(unsigned u) { return __uint_as_float(u & 0xffff0000u); }
// uint index of 16B chunk base, swizzled
static __device__ __forceinline__ int swz(int row, int chunk) {
    return row * 32 + ((chunk ^ (row & 7)) << 2);
}

// ---------- prep: pack W into A-fragments + head transposes ----------
// fragid = ((((buf*4+lvl)*2+Kt)*3+tap)*4+m)*2+s ; per frag: [lane][4 dwords]
// A-frag lane map (16x16x32 bf16): c = m*16 + (lane&15), i = Kt*32 + (lane>>4)*8 + j
__global__ __launch_bounds__(256) void prep_kernel(
    const float* __restrict__ w1, const float* __restrict__ w2,
    const float* __restrict__ aw, const float* __restrict__ fw,
    float* __restrict__ ws)
{
    int gid = blockIdx.x * 256 + threadIdx.x;
    if (gid < 24576) {
        int frag = gid >> 6, lane = gid & 63;
        int s   = frag & 1;
        int m   = (frag >> 1) & 3;
        int t3  = frag >> 3;
        int tap = t3 % 3;
        int q   = t3 / 3;
        int Kt  = q & 1;
        int lvl = (q >> 1) & 3;
        int buf = q >> 3;
        int c  = m * 16 + (lane & 15);
        int i0 = Kt * 32 + (lane >> 4) * 8;
        const float* W = (buf ? w2 : w1) + lvl * 12288 + c * 192;
        unsigned short v[8];
        for (int j = 0; j < 8; ++j) {
            float x = W[(i0 + j) * 3 + tap];
            unsigned short hi = f2bf(x);
            if (s == 0) v[j] = hi;
            else        v[j] = f2bf(x - bf2f(hi));
        }
        unsigned* dst = (unsigned*)ws + frag * 256 + lane * 4;
        for (int d = 0; d < 4; ++d)
            dst[d] = (unsigned)v[2 * d] | ((unsigned)v[2 * d + 1] << 16);
    }
    if (gid < 32000) {
        int a = gid >> 6, c = gid & 63;   // src [a][c]
        ws[OFF_AWT + c * 500 + a] = aw[gid];
        ws[OFF_FWT + c * 500 + a] = fw[gid];
    }
}

extern __shared__ unsigned short lds[];

#define MFMA(A, B, C) __builtin_amdgcn_mfma_f32_16x16x32_bf16((A), (B), (C), 0, 0, 0)

__global__ __launch_bounds__(256, 2) void conv_kernel(
    const float* __restrict__ x,
    const float* __restrict__ ws,
    const float* __restrict__ b1,
    const float* __restrict__ b2,
    float* __restrict__ pooled)
{
    const int b    = blockIdx.x;
    const int tid  = threadIdx.x;        // 0..255
    const int lane = tid & 63;
    const int wv   = tid >> 6;           // 4 waves; wave handles ntiles 4wv..4wv+3

    unsigned* Lh = (unsigned*)lds;
    unsigned* Ll = Lh + PLANE_U;

    // zero pad rows 0..15 (t<0) and 268..271 (t>=252), both planes (whole rows)
    for (int j = tid; j < 640; j += 256) {
        int r20 = j >> 5, col = j & 31;
        int r = (r20 < 16) ? r20 : (252 + r20);
        Lh[r * 32 + col] = 0u;
        Ll[r * 32 + col] = 0u;
    }
    // ingest x[b]: [252][64] fp32 -> split hi/lo bf16 planes (swizzled)
    const float4* xb = (const float4*)(x + (size_t)b * (T * 64));
    for (int v = tid; v < T * 16; v += 256) {
        float4 xv = xb[v];
        int t = v >> 4, f4 = v & 15;              // channel base = 4*f4
        unsigned h01 = pk2bf(xv.x, xv.y);
        unsigned h23 = pk2bf(xv.z, xv.w);
        unsigned l01 = pk2bf(xv.x - bf_lo_f(h01), xv.y - bf_hi_f(h01));
        unsigned l23 = pk2bf(xv.z - bf_lo_f(h23), xv.w - bf_hi_f(h23));
        int row = 16 + t;
        int ui = swz(row, f4 >> 1) + ((f4 & 1) << 1);
        Lh[ui]     = h01;
        Lh[ui + 1] = h23;
        Ll[ui]     = l01;
        Ll[ui + 1] = l23;
    }
    __syncthreads();

    const uint4* AF4 = (const uint4*)ws;
    const int g    = lane >> 4;               // 0..3
    const int g4   = g << 2;
    const int ln16 = lane & 15;

    uint2 hh[4][4], hl[4][4];                 // saved h_old at D-tiles (hi/lo packed)

    for (int lvl = 0; lvl < 4; ++lvl) {
        const int d = 1 << lvl;
        for (int cv = 0; cv < 2; ++cv) {
            const float* bias = (cv ? b2 : b1) + lvl * 64;
            f32x4 acc[4][4];
            #pragma unroll
            for (int m = 0; m < 4; ++m) {
                float4 bv = *(const float4*)(bias + m * 16 + g4);
                #pragma unroll
                for (int nn = 0; nn < 4; ++nn)
                    acc[m][nn] = (f32x4){bv.x, bv.y, bv.z, bv.w};
            }

            #pragma unroll
            for (int Kt = 0; Kt < 2; ++Kt) {
                #pragma unroll
                for (int tap = 0; tap < 3; ++tap) {
                    const int shift = (2 - tap) * d;
                    const int fb = (((cv * 4 + lvl) * 2 + Kt) * 3 + tap) * 8;
                    bf8 Bh[4], Bl[4];
                    #pragma unroll
                    for (int nn = 0; nn < 4; ++nn) {
                        int row = 16 + (4 * wv + nn) * 16 + ln16 - shift;
                        int ui  = swz(row, Kt * 4 + g);
                        Bh[nn] = *(const bf8*)(Lh + ui);
                        Bl[nn] = *(const bf8*)(Ll + ui);
                    }
                    #pragma unroll
                    for (int m = 0; m < 4; ++m) {
                        uint4 ta = AF4[(fb + 2 * m) * 64 + lane];
                        uint4 tb = AF4[(fb + 2 * m + 1) * 64 + lane];
                        bf8 Ah = *(bf8*)&ta;
                        bf8 Al = *(bf8*)&tb;
                        #pragma unroll
                        for (int nn = 0; nn < 4; ++nn) {
                            f32x4 a = acc[m][nn];
                            a = MFMA(Ah, Bh[nn], a);
                            a = MFMA(Ah, Bl[nn], a);   // hi*lo
                            a = MFMA(Al, Bh[nn], a);   // lo*hi (lo*lo dropped: ~2^-18)
                            acc[m][nn] = a;
                        }
                    }
                }
            }

            // epilogue: D map: t = ntile*16 + ln16, c = m*16 + g4 + reg
            if (cv == 0) {
                #pragma unroll
                for (int m = 0; m < 4; ++m)
                    #pragma unroll
                    for (int nn = 0; nn < 4; ++nn) {
                        int row = 16 + (4 * wv + nn) * 16 + ln16;
                        int cd  = m * 8 + (g4 >> 1);       // even -> 8B aligned
                        int ui  = swz(row, cd >> 2) + (cd & 3);
                        hh[m][nn] = *(uint2*)(Lh + ui);
                        hl[m][nn] = *(uint2*)(Ll + ui);
                    }
                __syncthreads();   // all reads of h_old done
                #pragma unroll
                for (int m = 0; m < 4; ++m) {
                    #pragma unroll
                    for (int nn = 0; nn < 4; ++nn) {
                        int row = 16 + (4 * wv + nn) * 16 + ln16;
                        int cd  = m * 8 + (g4 >> 1);
                        int ui  = swz(row, cd >> 2) + (cd & 3);
                        float o0 = fmaxf(acc[m][nn][0], 0.f);
                        float o1 = fmaxf(acc[m][nn][1], 0.f);
                        float o2 = fmaxf(acc[m][nn][2], 0.f);
                        float o3 = fmaxf(acc[m][nn][3], 0.f);
                        uint2 wh, wl;
                        wh.x = pk2bf(o0, o1);
                        wh.y = pk2bf(o2, o3);
                        wl.x = pk2bf(o0 - bf_lo_f(wh.x), o1 - bf_hi_f(wh.x));
                        wl.y = pk2bf(o2 - bf_lo_f(wh.y), o3 - bf_hi_f(wh.y));
                        *(uint2*)(Lh + ui) = wh;
                        *(uint2*)(Ll + ui) = wl;
                    }
                }
                __syncthreads();   // o1 visible
            } else {
                __syncthreads();   // all reads of o1 done
                #pragma unroll
                for (int m = 0; m < 4; ++m) {
                    #pragma unroll
                    for (int nn = 0; nn < 4; ++nn) {
                        int row = 16 + (4 * wv + nn) * 16 + ln16;
                        int cd  = m * 8 + (g4 >> 1);
                        int ui  = swz(row, cd >> 2) + (cd & 3);
                        float hold0 = bf_lo_f(hh[m][nn].x) + bf_lo_f(hl[m][nn].x);
                        float hold1 = bf_hi_f(hh[m][nn].x) + bf_hi_f(hl[m][nn].x);
                        float hold2 = bf_lo_f(hh[m][nn].y) + bf_lo_f(hl[m][nn].y);
                        float hold3 = bf_hi_f(hh[m][nn].y) + bf_hi_f(hl[m][nn].y);
                        float h0 = fmaxf(fmaxf(acc[m][nn][0], 0.f) + hold0, 0.f);
                        float h1 = fmaxf(fmaxf(acc[m][nn][1], 0.f) + hold1, 0.f);
                        float h2 = fmaxf(fmaxf(acc[m][nn][2], 0.f) + hold2, 0.f);
                        float h3 = fmaxf(fmaxf(acc[m][nn][3], 0.f) + hold3, 0.f);
                        uint2 wh, wl;
                        wh.x = pk2bf(h0, h1);
                        wh.y = pk2bf(h2, h3);
                        wl.x = pk2bf(h0 - bf_lo_f(wh.x), h1 - bf_hi_f(wh.x));
                        wl.y = pk2bf(h2 - bf_lo_f(wh.y), h3 - bf_hi_f(wh.y));
                        *(uint2*)(Lh + ui) = wh;
                        *(uint2*)(Ll + ui) = wl;
                    }
                }
                __syncthreads();   // h_new visible
            }
        }
    }

    // ---- max-pool over t (values >= 0 after relu) ----
    {
        int c = tid & 63, part = tid >> 6;     // 4 parts x 63 t = 252
        int cd = c >> 1;
        float mx = 0.f;
        for (int j = 0; j < 63; ++j) {
            int row = 16 + part * 63 + j;
            int ui = swz(row, cd >> 2) + (cd & 3);
            int us = 2 * ui + (c & 1);
            mx = fmaxf(mx, bf2f(lds[us]) + bf2f(lds[2 * PLANE_U + us]));
        }
        __syncthreads();
        ((float*)lds)[tid] = mx;
        __syncthreads();
        if (tid < 64) {
            float* fs = (float*)lds;
            float mm = fmaxf(fmaxf(fs[tid], fs[tid + 64]),
                             fmaxf(fs[tid + 128], fs[tid + 192]));
            pooled[(size_t)b * 64 + tid] = mm;
        }
    }
}

// ---------- head: GEMVs + wave-local top-20 + softmax + wave-local rebalance ----------
__global__ __launch_bounds__(256) void head_kernel(
    const float* __restrict__ ws,
    const float* __restrict__ proj_w,
    const float* __restrict__ proj_b,
    const float* __restrict__ attn_b,
    const float* __restrict__ fc_b,
    float* __restrict__ out)
{
    const float* awT    = ws + OFF_AWT;
    const float* fwT    = ws + OFF_FWT;
    const float* pooled = ws + OFF_POOLED;

    __shared__ float z[64];
    __shared__ float att[512];
    __shared__ float pa[512];
    __shared__ int   msk[512];
    __shared__ float rs[4];

    const int b   = blockIdx.x;
    const int tid = threadIdx.x;
    const int wv  = tid >> 6, ln = tid & 63;

    // z = relu(pooled @ proj_w^T + proj_b)
    if (tid < 64) {
        float s = proj_b[tid];
        const float* pw = proj_w + tid * 64;
        const float* pl = pooled + (size_t)b * 64;
        #pragma unroll 8
        for (int c = 0; c < 64; ++c) s = fmaf(pw[c], pl[c], s);
        z[tid] = fmaxf(s, 0.f);
    }
    __syncthreads();

    const int a0  = tid;
    const int a1  = tid + 256;
    const int a1e = (a1 < NOUT) ? a1 : (NOUT - 1);

    // attn = sigmoid(z @ attn_w^T + attn_b); fc logits too (independent of top-k)
    float l0 = attn_b[a0], l1 = attn_b[a1e];
    float f0 = fc_b[a0],   f1 = fc_b[a1e];
    #pragma unroll 8
    for (int c = 0; c < 64; ++c) {
        float zc = z[c];
        l0 = fmaf(zc, awT[c * 500 + a0],  l0);
        l1 = fmaf(zc, awT[c * 500 + a1e], l1);
        f0 = fmaf(zc, fwT[c * 500 + a0],  f0);
        f1 = fmaf(zc, fwT[c * 500 + a1e], f1);
    }
    float v0 = 1.f / (1.f + expf(-l0));
    float v1 = (a1 < NOUT) ? 1.f / (1.f + expf(-l1)) : 0.f;
    if (a1 >= NOUT) f1 = -1e30f;
    att[a0] = v0; att[a1] = v1;
    msk[a0] = 0;  msk[a1] = 0;
    __syncthreads();

    // wave 0: top-20 over 500 sigmoids (ties -> lower index, matching lax.top_k)
    int selidx = 0;
    if (wv == 0) {
        float va[8];
        #pragma unroll
        for (int j = 0; j < 8; ++j) {
            int id = j * 64 + ln;
            va[j] = (id < NOUT) ? att[id] : 0.f;   // sigmoid > 0 for valid
        }
        for (int s = 0; s < NSEL; ++s) {
            float bv = va[0]; int bj = 0;
            #pragma unroll
            for (int j = 1; j < 8; ++j)
                if (va[j] > bv) { bv = va[j]; bj = j; }
            unsigned long long k =
                ((unsigned long long)__float_as_uint(bv) << 32)
                | (unsigned)(0xFFFFFFFFu - (unsigned)(bj * 64 + ln));
            for (int o = 32; o > 0; o >>= 1) {
                unsigned long long other = __shfl_xor(k, o);
                if (other > k) k = other;
            }
            int widx = (int)(0xFFFFFFFFu - (unsigned)(k & 0xFFFFFFFFu));
            if (ln == s) selidx = widx;
            if ((widx & 63) == ln) va[widx >> 6] = 0.f;
            if (ln == 0) msk[widx] = 1;
        }
    }
    __syncthreads();

    // softmax over all 500
    float mx = fmaxf(f0, f1);
    for (int o = 32; o > 0; o >>= 1) mx = fmaxf(mx, __shfl_xor(mx, o));
    if (ln == 0) rs[wv] = mx;
    __syncthreads();
    mx = fmaxf(fmaxf(rs[0], rs[1]), fmaxf(rs[2], rs[3]));
    __syncthreads();
    float e0 = expf(f0 - mx);
    float e1 = (a1 < NOUT) ? expf(f1 - mx) : 0.f;
    float sm = e0 + e1;
    for (int o = 32; o > 0; o >>= 1) sm += __shfl_xor(sm, o);
    if (ln == 0) rs[wv] = sm;
    __syncthreads();
    float Z = rs[0] + rs[1] + rs[2] + rs[3];

    float p0 = msk[a0] ? (e0 / Z) : 0.f;
    float p1 = (a1 < NOUT && msk[a1]) ? (e1 / Z) : 0.f;
    pa[a0] = p0; pa[a1] = p1;
    __syncthreads();

    // wave 0: renormalize + 17-iter water-filling on the 20 selected
    // (unselected weights are exactly 0.0 and are fixed points of the update)
    if (wv == 0) {
        float w = (ln < NSEL) ? pa[selidx] : 0.f;
        float S = w;
        for (int o = 32; o > 0; o >>= 1) S += __shfl_xor(S, o);
        w = w / (S + 1e-8f);
        for (int it = 0; it < 17; ++it) {
            float wc = fminf(fmaxf(w, 0.f), UBV);
            float lo = w - wc;
            float ns = (wc != UBV) ? wc : 0.f;
            for (int o = 32; o > 0; o >>= 1) {
                lo += __shfl_xor(lo, o);
                ns += __shfl_xor(ns, o);
            }
            if (ns == 0.f) ns = 1.f;
            w = (wc != UBV) ? wc + lo * wc / ns : wc;
        }
        if (ln < NSEL) out[(size_t)b * NOUT + selidx] = w;
    }
    if (!msk[a0]) out[(size_t)b * NOUT + a0] = 0.f;
    if (a1 < NOUT && !msk[a1]) out[(size_t)b * NOUT + a1] = 0.f;
}

extern "C" void kernel_launch(void* const* d_in, const int* in_sizes, int n_in,
                              void* d_out, int out_size, void* d_ws, size_t ws_size,
                              hipStream_t stream)
{
    const float* x   = (const float*)d_in[0];
    const float* c1w = (const float*)d_in[1];
    const float* c1b = (const float*)d_in[2];
    const float* c2w = (const float*)d_in[3];
    const float* c2b = (const float*)d_in[4];
    const float* pw  = (const float*)d_in[5];
    const float* pb  = (const float*)d_in[6];
    const float* aw  = (const float*)d_in[7];
    const float* ab  = (const float*)d_in[8];
    const float* fw  = (const float*)d_in[9];
    const float* fb  = (const float*)d_in[10];

    float* ws  = (float*)d_ws;
    float* out = (float*)d_out;

    (void)hipFuncSetAttribute((const void*)conv_kernel,
                              hipFuncAttributeMaxDynamicSharedMemorySize,
                              LDS_BYTES);

    prep_kernel<<<128, 256, 0, stream>>>(c1w, c2w, aw, fw, ws);
    conv_kernel<<<2048, 256, LDS_BYTES, stream>>>(x, ws, c1b, c2b, ws + OFF_POOLED);
    head_kernel<<<2048, 256, 0, stream>>>(ws, pw, pb, ab, fb, out);
}